// Round 3
// baseline (12603.535 us; speedup 1.0000x reference)
//
#include <hip/hip_runtime.h>
#include <math.h>

// GRU rollout: hidden-dim split across wgs, weights read via wave-uniform
// global loads (-> s_load SGPR path, no LDS), per-step sync via relaunch.
//
// Fusions (exact fp32 algebra):
//   p_{s-1} = h_{s-1} @ Wp^T + bp   =>   x_s = [p_{s-1}, lat, lon]
//   gi = h_{s-1} @ Wf^T + const,  Wf = Wih[:,:256] @ Wp  (precomputed once)
//   r,z rows combined: Wc_rz = Wf_rz + Whh_rz ; n rows kept separate.
// Per hidden unit: 4 dots of K=512. Each wg: 4 units + 2 proj rows.
// Step 1 uses true x_1 = [p0, lat, lon] via precomputed gi1.

#define B_SZ   2048
#define LAT    256
#define HID    512
#define NTHR   512
#define NWG    512          // 4 batch groups x 128 wgs
#define HBUF   (B_SZ * HID) // one h buffer (row-major), floats

__device__ __forceinline__ float sigm(float x) {
    return 1.0f / (1.0f + __expf(-x));
}
__device__ __forceinline__ float tanh_f(float x) {
    float e = __expf(-2.0f * fabsf(x));
    float t = (1.0f - e) / (1.0f + e);
    return copysignf(t, x);
}

// ---------------- precompute: Wc[512 units][4][512] ----------------
// rows per unit u: [0]=Wf_r+Whh_r, [1]=Wf_z+Whh_z, [2]=Wf_n, [3]=Whh_n
__global__ __launch_bounds__(512) void k_wf(
    const float* __restrict__ W_ih, const float* __restrict__ W_hh,
    const float* __restrict__ W_pr, float* __restrict__ Wc)
{
    const int u = blockIdx.x;     // hidden unit
    const int k = threadIdx.x;    // output column
    __shared__ float wih_s[3][256];
    for (int i = threadIdx.x; i < 3 * 256; i += 512) {
        int j = i >> 8, o = i & 255;
        wih_s[j][o] = W_ih[(size_t)(j * HID + u) * 258 + o];
    }
    __syncthreads();
    float fr = 0.f, fz = 0.f, fn = 0.f;
    for (int o = 0; o < 256; ++o) {
        float wp = W_pr[(size_t)o * HID + k];
        fr = fmaf(wih_s[0][o], wp, fr);
        fz = fmaf(wih_s[1][o], wp, fz);
        fn = fmaf(wih_s[2][o], wp, fn);
    }
    float* dst = Wc + (size_t)u * 4 * HID;
    dst[0 * HID + k] = fr + W_hh[(size_t)u * HID + k];
    dst[1 * HID + k] = fz + W_hh[(size_t)(HID + u) * HID + k];
    dst[2 * HID + k] = fn;
    dst[3 * HID + k] = W_hh[(size_t)(2 * HID + u) * HID + k];
}

// ---------------- precompute: Bias[512][12], parallel ----------------
// [0]Br(+bhh) [1]c1r [2]c2r [3]Bz(+bhh) [4]c1z [5]c2z
// [6]Bn_i     [7]c1n [8]c2n [9]bhh_n [10]bhh_r [11]bhh_z
__global__ __launch_bounds__(64) void k_bias(
    const float* __restrict__ W_ih, const float* __restrict__ b_ih,
    const float* __restrict__ b_hh, const float* __restrict__ b_pr,
    float* __restrict__ Bias)
{
    const int u = blockIdx.x;
    const int t = threadIdx.x;
    float dr = 0.f, dz = 0.f, dn = 0.f;
    for (int o = t; o < 256; o += 64) {
        float bo = b_pr[o];
        dr = fmaf(bo, W_ih[(size_t)u * 258 + o], dr);
        dz = fmaf(bo, W_ih[(size_t)(HID + u) * 258 + o], dz);
        dn = fmaf(bo, W_ih[(size_t)(2 * HID + u) * 258 + o], dn);
    }
    #pragma unroll
    for (int off = 32; off > 0; off >>= 1) {
        dr += __shfl_down(dr, off);
        dz += __shfl_down(dz, off);
        dn += __shfl_down(dn, off);
    }
    if (t == 0) {
        float* b = Bias + u * 12;
        b[0]  = b_ih[u] + b_hh[u] + dr;
        b[1]  = W_ih[(size_t)u * 258 + 256];
        b[2]  = W_ih[(size_t)u * 258 + 257];
        b[3]  = b_ih[HID + u] + b_hh[HID + u] + dz;
        b[4]  = W_ih[(size_t)(HID + u) * 258 + 256];
        b[5]  = W_ih[(size_t)(HID + u) * 258 + 257];
        b[6]  = b_ih[2 * HID + u] + dn;
        b[7]  = W_ih[(size_t)(2 * HID + u) * 258 + 256];
        b[8]  = W_ih[(size_t)(2 * HID + u) * 258 + 257];
        b[9]  = b_hh[2 * HID + u];
        b[10] = b_hh[u];
        b[11] = b_hh[HID + u];
    }
}

// ---------------- precompute: gi1_T[1536][2048] = x1 @ Wih^T + b_ih; out[0]=p0
__global__ __launch_bounds__(512) void k_gi1(
    const float* __restrict__ p0, const float* __restrict__ latv,
    const float* __restrict__ lonv, const float* __restrict__ W_ih,
    const float* __restrict__ b_ih, float* __restrict__ gi1T,
    float* __restrict__ out)
{
    const int rb = blockIdx.x;            // 256 blocks x 8 rows
    const int t  = threadIdx.x;
    __shared__ float p0s[8][256];
    __shared__ float lat_s[8], lon_s[8];
    for (int i = t; i < 8 * 256; i += 512) {
        int r = i >> 8, o = i & 255;
        float v = p0[(size_t)(rb * 8 + r) * LAT + o];
        p0s[r][o] = v;
        out[(size_t)(rb * 8 + r) * LAT + o] = v;   // out[0] = p0
    }
    if (t < 8) { lat_s[t] = latv[rb * 8 + t]; lon_s[t] = lonv[rb * 8 + t]; }
    __syncthreads();

    for (int gg = 0; gg < 3; ++gg) {
        const int grow = t + gg * 512;
        const float* wr = W_ih + (size_t)grow * 258;
        float acc[8];
        float bi = b_ih[grow];
        #pragma unroll
        for (int r = 0; r < 8; ++r) acc[r] = bi;
        for (int o = 0; o < 256; ++o) {
            float wv = wr[o];
            #pragma unroll
            for (int r = 0; r < 8; ++r) acc[r] = fmaf(wv, p0s[r][o], acc[r]);
        }
        float c1 = wr[256], c2 = wr[257];
        #pragma unroll
        for (int r = 0; r < 8; ++r) {
            acc[r] = fmaf(lat_s[r], c1, acc[r]);
            acc[r] = fmaf(lon_s[r], c2, acc[r]);
            gi1T[(size_t)grow * B_SZ + rb * 8 + r] = acc[r];
        }
    }
}

// ---------------- main step kernel (one launch per time step) ----------------
// No LDS. Weights read with wave-uniform addresses -> SGPR s_load path.
// h stored row-major [B][HID], double-buffered.
__global__ __launch_bounds__(NTHR) void k_step(
    const float* __restrict__ Wc, const float* __restrict__ Bias,
    const float* __restrict__ W_pr, const float* __restrict__ b_pr,
    const float* __restrict__ gi1T, const float* __restrict__ latv,
    const float* __restrict__ lonv, float* __restrict__ hT,
    float* __restrict__ out, int s, int ns)
{
    const int gid = blockIdx.x;
    const int g   = (gid & 7) >> 1;                 // batch group 0..3
    const int w   = ((gid >> 3) << 1) | (gid & 1);  // wg-in-group 0..127
    const int u0  = w * 4;                          // 4 hidden units
    const int o0  = w * 2;                          // 2 proj columns
    const int t   = threadIdx.x;
    const int row = g * 512 + t;                    // global batch row

    const float* __restrict__ hcur = hT + (size_t)((s - 1) & 1) * HBUF;
    float*       __restrict__ hnxt = hT + (size_t)(s & 1) * HBUF;

    float a[16];                 // [unit][gate] accumulators
    float ap0 = 0.f, ap1 = 0.f;  // projection accumulators
    #pragma unroll
    for (int i = 0; i < 16; ++i) a[i] = 0.f;

    if (s >= 2) {
        const float4* __restrict__ hrow4 = (const float4*)(hcur + (size_t)row * HID);
        const float4* __restrict__ wb4   = (const float4*)(Wc + (size_t)u0 * 4 * HID);
        const float4* __restrict__ wp4   = (const float4*)(W_pr + (size_t)o0 * HID);
        for (int kq = 0; kq < HID / 4; ++kq) {
            float4 hv = hrow4[kq];
            #pragma unroll
            for (int r = 0; r < 16; ++r) {
                float4 wv = wb4[kq + r * (HID / 4)];   // wave-uniform -> s_load
                a[r] = fmaf(wv.x, hv.x, a[r]);
                a[r] = fmaf(wv.y, hv.y, a[r]);
                a[r] = fmaf(wv.z, hv.z, a[r]);
                a[r] = fmaf(wv.w, hv.w, a[r]);
            }
            {
                float4 wv = wp4[kq];
                ap0 = fmaf(wv.x, hv.x, ap0); ap0 = fmaf(wv.y, hv.y, ap0);
                ap0 = fmaf(wv.z, hv.z, ap0); ap0 = fmaf(wv.w, hv.w, ap0);
                wv = wp4[kq + (HID / 4)];
                ap1 = fmaf(wv.x, hv.x, ap1); ap1 = fmaf(wv.y, hv.y, ap1);
                ap1 = fmaf(wv.z, hv.z, ap1); ap1 = fmaf(wv.w, hv.w, ap1);
            }
        }
    }

    // ---- gates -> h_s ----
    if (s <= ns) {
        const float lt = latv[row], ln = lonv[row];
        float4 holdv = make_float4(0.f, 0.f, 0.f, 0.f);
        if (s >= 2) holdv = *(const float4*)(hcur + (size_t)row * HID + u0);
        float hnew[4];
        #pragma unroll
        for (int u = 0; u < 4; ++u) {
            const float* bb = Bias + (size_t)(u0 + u) * 12;  // uniform -> s_load
            float pre_r, pre_z, i_n, h_n, hold;
            hold = (u == 0) ? holdv.x : (u == 1) ? holdv.y : (u == 2) ? holdv.z : holdv.w;
            if (s == 1) {
                pre_r = gi1T[(size_t)(u0 + u) * B_SZ + row] + bb[10];
                pre_z = gi1T[(size_t)(HID + u0 + u) * B_SZ + row] + bb[11];
                i_n   = gi1T[(size_t)(2 * HID + u0 + u) * B_SZ + row];
                h_n   = bb[9];
            } else {
                pre_r = a[u * 4 + 0] + bb[0] + lt * bb[1] + ln * bb[2];
                pre_z = a[u * 4 + 1] + bb[3] + lt * bb[4] + ln * bb[5];
                i_n   = a[u * 4 + 2] + bb[6] + lt * bb[7] + ln * bb[8];
                h_n   = a[u * 4 + 3] + bb[9];
            }
            float r = sigm(pre_r);
            float z = sigm(pre_z);
            float n = tanh_f(fmaf(r, h_n, i_n));
            hnew[u] = n + z * (hold - n);
        }
        *(float4*)(hnxt + (size_t)row * HID + u0) =
            make_float4(hnew[0], hnew[1], hnew[2], hnew[3]);
    }

    // ---- output p_{s-1} ----
    if (s >= 2) {
        float* orow = out + (size_t)(s - 1) * B_SZ * LAT + (size_t)row * LAT;
        orow[o0]     = ap0 + b_pr[o0];
        orow[o0 + 1] = ap1 + b_pr[o0 + 1];
    }
}

extern "C" void kernel_launch(void* const* d_in, const int* in_sizes, int n_in,
                              void* d_out, int out_size, void* d_ws, size_t ws_size,
                              hipStream_t stream)
{
    const float* p0   = (const float*)d_in[0];
    const float* latv = (const float*)d_in[1];
    const float* lonv = (const float*)d_in[2];
    const float* W_ih = (const float*)d_in[3];
    const float* W_hh = (const float*)d_in[4];
    const float* b_ih = (const float*)d_in[5];
    const float* b_hh = (const float*)d_in[6];
    const float* W_pr = (const float*)d_in[7];
    const float* b_pr = (const float*)d_in[8];
    float* out = (float*)d_out;

    const int NS = out_size / (B_SZ * LAT) - 1;   // 100

    // workspace layout (floats)
    float* hT   = (float*)d_ws;                   // 2 * 2048 * 512
    float* gi1T = hT + 2 * HBUF;                  // 1536 * 2048
    float* Wc   = gi1T + 3 * HID * B_SZ;          // 512 * 4 * 512
    float* Bias = Wc + (size_t)HID * 4 * HID;     // 512 * 12

    hipLaunchKernelGGL(k_wf,   dim3(HID), dim3(512), 0, stream, W_ih, W_hh, W_pr, Wc);
    hipLaunchKernelGGL(k_bias, dim3(HID), dim3(64),  0, stream, W_ih, b_ih, b_hh, b_pr, Bias);
    hipLaunchKernelGGL(k_gi1,  dim3(256), dim3(512), 0, stream, p0, latv, lonv, W_ih, b_ih, gi1T, out);

    for (int s = 1; s <= NS + 1; ++s) {
        hipLaunchKernelGGL(k_step, dim3(NWG), dim3(NTHR), 0, stream,
                           Wc, Bias, W_pr, b_pr, gi1T, latv, lonv, hT, out, s, NS);
    }
}

// Round 4
// 11569.714 us; speedup vs baseline: 1.0894x; 1.0894x over previous
//
#include <hip/hip_runtime.h>
#include <math.h>

// GRU rollout: hidden-dim split across wgs, weights LDS-resident read as
// float4 BROADCASTS (ds_read_b128, wave-uniform addr -> conflict-free),
// h row-major, per-step sync via kernel relaunch.
//
// Fusions (exact fp32 algebra):
//   p_{s-1} = h_{s-1} @ Wp^T + bp   =>   x_s = [p_{s-1}, lat, lon]
//   gi = h_{s-1} @ Wf^T + const,  Wf = Wih[:,:256] @ Wp  (precomputed once)
//   r,z rows combined: Wc_rz = Wf_rz + Whh_rz ; n rows kept separate.
// Per hidden unit: 4 dots of K=512. Each wg: 4 units + 2 proj rows.
// Step 1 uses true x_1 = [p0, lat, lon] via precomputed gi1.

#define B_SZ   2048
#define LAT    256
#define HID    512
#define NTHR   512
#define NWG    512          // 4 batch groups x 128 wgs
#define HBUF   (B_SZ * HID) // one h buffer (row-major), floats

__device__ __forceinline__ float sigm(float x) {
    return 1.0f / (1.0f + __expf(-x));
}
__device__ __forceinline__ float tanh_f(float x) {
    float e = __expf(-2.0f * fabsf(x));
    float t = (1.0f - e) / (1.0f + e);
    return copysignf(t, x);
}

// ---------------- precompute: Wc[512 units][4][512] ----------------
// rows per unit u: [0]=Wf_r+Whh_r, [1]=Wf_z+Whh_z, [2]=Wf_n, [3]=Whh_n
__global__ __launch_bounds__(512) void k_wf(
    const float* __restrict__ W_ih, const float* __restrict__ W_hh,
    const float* __restrict__ W_pr, float* __restrict__ Wc)
{
    const int u = blockIdx.x;     // hidden unit
    const int k = threadIdx.x;    // output column
    __shared__ float wih_s[3][256];
    for (int i = threadIdx.x; i < 3 * 256; i += 512) {
        int j = i >> 8, o = i & 255;
        wih_s[j][o] = W_ih[(size_t)(j * HID + u) * 258 + o];
    }
    __syncthreads();
    float fr = 0.f, fz = 0.f, fn = 0.f;
    for (int o = 0; o < 256; ++o) {
        float wp = W_pr[(size_t)o * HID + k];
        fr = fmaf(wih_s[0][o], wp, fr);
        fz = fmaf(wih_s[1][o], wp, fz);
        fn = fmaf(wih_s[2][o], wp, fn);
    }
    float* dst = Wc + (size_t)u * 4 * HID;
    dst[0 * HID + k] = fr + W_hh[(size_t)u * HID + k];
    dst[1 * HID + k] = fz + W_hh[(size_t)(HID + u) * HID + k];
    dst[2 * HID + k] = fn;
    dst[3 * HID + k] = W_hh[(size_t)(2 * HID + u) * HID + k];
}

// ---------------- precompute: Bias[512][12], parallel ----------------
// [0]Br(+bhh) [1]c1r [2]c2r [3]Bz(+bhh) [4]c1z [5]c2z
// [6]Bn_i     [7]c1n [8]c2n [9]bhh_n [10]bhh_r [11]bhh_z
__global__ __launch_bounds__(64) void k_bias(
    const float* __restrict__ W_ih, const float* __restrict__ b_ih,
    const float* __restrict__ b_hh, const float* __restrict__ b_pr,
    float* __restrict__ Bias)
{
    const int u = blockIdx.x;
    const int t = threadIdx.x;
    float dr = 0.f, dz = 0.f, dn = 0.f;
    for (int o = t; o < 256; o += 64) {
        float bo = b_pr[o];
        dr = fmaf(bo, W_ih[(size_t)u * 258 + o], dr);
        dz = fmaf(bo, W_ih[(size_t)(HID + u) * 258 + o], dz);
        dn = fmaf(bo, W_ih[(size_t)(2 * HID + u) * 258 + o], dn);
    }
    #pragma unroll
    for (int off = 32; off > 0; off >>= 1) {
        dr += __shfl_down(dr, off);
        dz += __shfl_down(dz, off);
        dn += __shfl_down(dn, off);
    }
    if (t == 0) {
        float* b = Bias + u * 12;
        b[0]  = b_ih[u] + b_hh[u] + dr;
        b[1]  = W_ih[(size_t)u * 258 + 256];
        b[2]  = W_ih[(size_t)u * 258 + 257];
        b[3]  = b_ih[HID + u] + b_hh[HID + u] + dz;
        b[4]  = W_ih[(size_t)(HID + u) * 258 + 256];
        b[5]  = W_ih[(size_t)(HID + u) * 258 + 257];
        b[6]  = b_ih[2 * HID + u] + dn;
        b[7]  = W_ih[(size_t)(2 * HID + u) * 258 + 256];
        b[8]  = W_ih[(size_t)(2 * HID + u) * 258 + 257];
        b[9]  = b_hh[2 * HID + u];
        b[10] = b_hh[u];
        b[11] = b_hh[HID + u];
    }
}

// ---------------- precompute: gi1_T[1536][2048] = x1 @ Wih^T + b_ih; out[0]=p0
__global__ __launch_bounds__(512) void k_gi1(
    const float* __restrict__ p0, const float* __restrict__ latv,
    const float* __restrict__ lonv, const float* __restrict__ W_ih,
    const float* __restrict__ b_ih, float* __restrict__ gi1T,
    float* __restrict__ out)
{
    const int rb = blockIdx.x;            // 256 blocks x 8 rows
    const int t  = threadIdx.x;
    __shared__ float p0s[8][256];
    __shared__ float lat_s[8], lon_s[8];
    for (int i = t; i < 8 * 256; i += 512) {
        int r = i >> 8, o = i & 255;
        float v = p0[(size_t)(rb * 8 + r) * LAT + o];
        p0s[r][o] = v;
        out[(size_t)(rb * 8 + r) * LAT + o] = v;   // out[0] = p0
    }
    if (t < 8) { lat_s[t] = latv[rb * 8 + t]; lon_s[t] = lonv[rb * 8 + t]; }
    __syncthreads();

    for (int gg = 0; gg < 3; ++gg) {
        const int grow = t + gg * 512;
        const float* wr = W_ih + (size_t)grow * 258;
        float acc[8];
        float bi = b_ih[grow];
        #pragma unroll
        for (int r = 0; r < 8; ++r) acc[r] = bi;
        for (int o = 0; o < 256; ++o) {
            float wv = wr[o];
            #pragma unroll
            for (int r = 0; r < 8; ++r) acc[r] = fmaf(wv, p0s[r][o], acc[r]);
        }
        float c1 = wr[256], c2 = wr[257];
        #pragma unroll
        for (int r = 0; r < 8; ++r) {
            acc[r] = fmaf(lat_s[r], c1, acc[r]);
            acc[r] = fmaf(lon_s[r], c2, acc[r]);
            gi1T[(size_t)grow * B_SZ + rb * 8 + r] = acc[r];
        }
    }
}

// ---------------- main step kernel (one launch per time step) ----------------
// Weights in LDS, read as float4 broadcasts. h row-major [B][HID], dbuffered.
__global__ __launch_bounds__(NTHR) void k_step(
    const float* __restrict__ Wc, const float* __restrict__ Bias,
    const float* __restrict__ W_pr, const float* __restrict__ b_pr,
    const float* __restrict__ gi1T, const float* __restrict__ latv,
    const float* __restrict__ lonv, float* __restrict__ hT,
    float* __restrict__ out, int s, int ns)
{
    const int gid = blockIdx.x;
    const int g   = (gid & 7) >> 1;                 // batch group 0..3
    const int w   = ((gid >> 3) << 1) | (gid & 1);  // wg-in-group 0..127
    const int u0  = w * 4;                          // 4 hidden units
    const int o0  = w * 2;                          // 2 proj columns
    const int t   = threadIdx.x;
    const int row = g * 512 + t;                    // global batch row

    __shared__ float wc[4][4][HID];    // 32 KB
    __shared__ float wp_s[2][HID];     // 4 KB
    __shared__ float bias_s[4][12];

    {
        const float4* src = (const float4*)(Wc + (size_t)u0 * 4 * HID);
        float4* dst = (float4*)wc;
        for (int i = t; i < 4 * 4 * HID / 4; i += NTHR) dst[i] = src[i];
        const float4* srcp = (const float4*)(W_pr + (size_t)o0 * HID);
        float4* dstp = (float4*)wp_s;
        for (int i = t; i < 2 * HID / 4; i += NTHR) dstp[i] = srcp[i];
        if (t < 48) ((float*)bias_s)[t] = Bias[u0 * 12 + t];
    }
    __syncthreads();

    const float* __restrict__ hcur = hT + (size_t)((s - 1) & 1) * HBUF;
    float*       __restrict__ hnxt = hT + (size_t)(s & 1) * HBUF;

    float a[16];                 // [unit][gate] accumulators
    float ap0 = 0.f, ap1 = 0.f;  // projection accumulators
    #pragma unroll
    for (int i = 0; i < 16; ++i) a[i] = 0.f;

    if (s >= 2) {
        const float4* __restrict__ hrow4 = (const float4*)(hcur + (size_t)row * HID);
        #pragma unroll 2
        for (int kq = 0; kq < HID / 4; ++kq) {
            float4 hv = hrow4[kq];
            #pragma unroll
            for (int u = 0; u < 4; ++u) {
                #pragma unroll
                for (int gg = 0; gg < 4; ++gg) {
                    float4 wv = *(const float4*)&wc[u][gg][4 * kq];  // b128 broadcast
                    a[u * 4 + gg] = fmaf(wv.x, hv.x, a[u * 4 + gg]);
                    a[u * 4 + gg] = fmaf(wv.y, hv.y, a[u * 4 + gg]);
                    a[u * 4 + gg] = fmaf(wv.z, hv.z, a[u * 4 + gg]);
                    a[u * 4 + gg] = fmaf(wv.w, hv.w, a[u * 4 + gg]);
                }
            }
            {
                float4 wv = *(const float4*)&wp_s[0][4 * kq];
                ap0 = fmaf(wv.x, hv.x, ap0); ap0 = fmaf(wv.y, hv.y, ap0);
                ap0 = fmaf(wv.z, hv.z, ap0); ap0 = fmaf(wv.w, hv.w, ap0);
                wv = *(const float4*)&wp_s[1][4 * kq];
                ap1 = fmaf(wv.x, hv.x, ap1); ap1 = fmaf(wv.y, hv.y, ap1);
                ap1 = fmaf(wv.z, hv.z, ap1); ap1 = fmaf(wv.w, hv.w, ap1);
            }
        }
    }

    // ---- gates -> h_s ----
    if (s <= ns) {
        const float lt = latv[row], ln = lonv[row];
        float4 holdv = make_float4(0.f, 0.f, 0.f, 0.f);
        if (s >= 2) holdv = *(const float4*)(hcur + (size_t)row * HID + u0);
        float hnew[4];
        #pragma unroll
        for (int u = 0; u < 4; ++u) {
            float pre_r, pre_z, i_n, h_n, hold;
            hold = (u == 0) ? holdv.x : (u == 1) ? holdv.y : (u == 2) ? holdv.z : holdv.w;
            if (s == 1) {
                pre_r = gi1T[(size_t)(u0 + u) * B_SZ + row] + bias_s[u][10];
                pre_z = gi1T[(size_t)(HID + u0 + u) * B_SZ + row] + bias_s[u][11];
                i_n   = gi1T[(size_t)(2 * HID + u0 + u) * B_SZ + row];
                h_n   = bias_s[u][9];
            } else {
                pre_r = a[u * 4 + 0] + bias_s[u][0] + lt * bias_s[u][1] + ln * bias_s[u][2];
                pre_z = a[u * 4 + 1] + bias_s[u][3] + lt * bias_s[u][4] + ln * bias_s[u][5];
                i_n   = a[u * 4 + 2] + bias_s[u][6] + lt * bias_s[u][7] + ln * bias_s[u][8];
                h_n   = a[u * 4 + 3] + bias_s[u][9];
            }
            float r = sigm(pre_r);
            float z = sigm(pre_z);
            float n = tanh_f(fmaf(r, h_n, i_n));
            hnew[u] = n + z * (hold - n);
        }
        *(float4*)(hnxt + (size_t)row * HID + u0) =
            make_float4(hnew[0], hnew[1], hnew[2], hnew[3]);
    }

    // ---- output p_{s-1} ----
    if (s >= 2) {
        float* orow = out + (size_t)(s - 1) * B_SZ * LAT + (size_t)row * LAT;
        orow[o0]     = ap0 + b_pr[o0];
        orow[o0 + 1] = ap1 + b_pr[o0 + 1];
    }
}

extern "C" void kernel_launch(void* const* d_in, const int* in_sizes, int n_in,
                              void* d_out, int out_size, void* d_ws, size_t ws_size,
                              hipStream_t stream)
{
    const float* p0   = (const float*)d_in[0];
    const float* latv = (const float*)d_in[1];
    const float* lonv = (const float*)d_in[2];
    const float* W_ih = (const float*)d_in[3];
    const float* W_hh = (const float*)d_in[4];
    const float* b_ih = (const float*)d_in[5];
    const float* b_hh = (const float*)d_in[6];
    const float* W_pr = (const float*)d_in[7];
    const float* b_pr = (const float*)d_in[8];
    float* out = (float*)d_out;

    const int NS = out_size / (B_SZ * LAT) - 1;   // 100

    // workspace layout (floats)
    float* hT   = (float*)d_ws;                   // 2 * 2048 * 512
    float* gi1T = hT + 2 * HBUF;                  // 1536 * 2048
    float* Wc   = gi1T + 3 * HID * B_SZ;          // 512 * 4 * 512
    float* Bias = Wc + (size_t)HID * 4 * HID;     // 512 * 12

    hipLaunchKernelGGL(k_wf,   dim3(HID), dim3(512), 0, stream, W_ih, W_hh, W_pr, Wc);
    hipLaunchKernelGGL(k_bias, dim3(HID), dim3(64),  0, stream, W_ih, b_ih, b_hh, b_pr, Bias);
    hipLaunchKernelGGL(k_gi1,  dim3(256), dim3(512), 0, stream, p0, latv, lonv, W_ih, b_ih, gi1T, out);

    for (int s = 1; s <= NS + 1; ++s) {
        hipLaunchKernelGGL(k_step, dim3(NWG), dim3(NTHR), 0, stream,
                           Wc, Bias, W_pr, b_pr, gi1T, latv, lonv, hT, out, s, NS);
    }
}